// Round 15
// baseline (120.087 us; speedup 1.0000x reference)
//
#include <hip/hip_runtime.h>
#include <stdint.h>

// Croston's method: B=8192 series x T=2048 steps. out = Z'/V' per step.
//
// Round 26 = Round 25 resubmitted verbatim (R25's bench was an infra
// failure: "MI355X container failed twice" -- no GPU evidence arrived).
//
// R25 rationale: R21 + ONE surgical lever: pin the series prefetch with a
// PERMISSIVE sched_barrier(0x387) (ALU|VALU|SALU|DS may cross; VMEM may
// not), placed right after the prefetch-load issue.
// Evidence chain: R22's profile showed VGPR_Count=72 -- buf[2][8](64) +
// xv(32) + scan state cannot coexist in 72 regs, so the scheduler SANK
// the prefetch loads to their use: R21/R24 ran wait->scan->store fully
// serialized, zero memory in flight during scans. That model reproduces
// every number: ~4.2us/series round, 16KB/round -> ~30 GB/s/CU -> ~3
// TB/s chip, invariant to stagger (R24 null: staggered-but-serial waves
// still have 33% memory duty each). R23's sched_barrier(0) regressed
// because mask-0 fences EVERYTHING (killed the scan's DS/VALU interleave);
// mask 0x387 pins only vmem order. Iteration order: consume buf[i] into
// LDS (counted vmcnt waits only those loads; prior stores stay pending)
// -> issue S(i+1) loads -> barrier(0x387) -> gather/scan/replay/store.
// Steady state: 8KB loads + 8KB stores in flight PER WAVE during scans.
// Diagnostic: VGPR_Count must rise to ~105-135, proving the pipeline
// exists in the emitted code. If VGPR rises and time doesn't move, the
// ~3 TB/s is a genuine service rate -> revert to R20, declare roofline.
// Everything else R21 verbatim: plain stores (NT refuted, R22), R19's
// verified swizzled transpose (row=G>>3, quad=(G&7)^((G>>3)&7)), fold
// (p==az) -> 6-round __shfl_up compose scan -> exclusive prefix ->
// replay. Exact; no warmup. 512 blocks, 8 waves/CU, 32KB LDS/block.

#define TLEN 2048

typedef float vf4 __attribute__((ext_vector_type(4)));

__global__ __launch_bounds__(256) void croston_kernel(
    const float* __restrict__ x,
    const float* __restrict__ alpha,
    const float* __restrict__ Z0,
    const float* __restrict__ V0,
    const float* __restrict__ q0,
    float* __restrict__ out)
{
    __shared__ __attribute__((aligned(16))) float lds[4][2048]; // 8KB/wave

    const int warp = threadIdx.x >> 6;
    const int lane = threadIdx.x & 63;
    const int wave = blockIdx.x * 4 + warp;   // 0..2047
    const int wid0 = wave * 4;                // 4 consecutive series
    float* W = lds[warp];                     // wave-private

    const float a  = alpha[0];
    const float ma = 1.0f - a;

    // R19 transpose addressing (verified):
    const int rg   = lane >> 3;                       // row-in-inst
    const int e    = (lane & 7) ^ rg;                 // write-side quad swizzle
    const int goff = rg * 32 + (e << 2);              // + j*256
    const int l7   = lane & 7;                        // read-side key
    const int lbase = lane * 32;

    // Hoist all 4 series' initial states (wave-uniform scalar loads).
    float zs[4], vs[4], qsx[4];
#pragma unroll
    for (int i = 0; i < 4; ++i) {
        zs[i]  = Z0[wid0 + i];
        vs[i]  = V0[wid0 + i];
        qsx[i] = q0[wid0 + i];
    }

    // ---- prologue: S0 -> buf0 ----
    vf4 buf[2][8];
#pragma unroll
    for (int j = 0; j < 8; ++j)
        buf[0][j] = *(const vf4*)(x + (size_t)wid0 * TLEN + j * 256 + lane * 4);

#pragma unroll
    for (int i = 0; i < 4; ++i) {              // fully unrolled: static idx
        const int wid = wid0 + i;

        // ---- transpose-in: consume buf[i&1] (compiler's counted vmcnt
        //      waits ONLY these loads; older stores keep draining) ----
#pragma unroll
        for (int j = 0; j < 8; ++j)
            *(vf4*)(W + j * 256 + goff) = buf[i & 1][j];

        // ---- issue S(i+1) prefetch into the freed buffer ----
        if (i < 3) {
#pragma unroll
            for (int j = 0; j < 8; ++j)
                buf[(i + 1) & 1][j] =
                    *(const vf4*)(x + (size_t)(wid + 1) * TLEN + j * 256 + lane * 4);
        }
        // VMEM may not cross (loads stay issued HERE, live across scan);
        // VALU/SALU/DS cross freely (scan scheduling untouched).
        __builtin_amdgcn_sched_barrier(0x387);

        vf4 xv[8];
#pragma unroll
        for (int m = 0; m < 8; ++m)
            xv[m] = *(const vf4*)(W + lbase + ((m ^ l7) << 2));

        // ---- fold: compose 32 per-step affine maps (p == az) ----
        float az = 1.f, bz = 0.f, r = 0.f, s = 0.f, f = 1.f, g = 0.f;
#pragma unroll
        for (int m = 0; m < 8; ++m) {
#pragma unroll
            for (int k = 0; k < 4; ++k) {
                const float xt = xv[m][k];
                const bool  nz = (xt != 0.f);
                const float az_n = ma * az;
                const float bz_n = fmaf(ma, bz, a * xt);
                const float r_n  = fmaf(ma, r, a * f);
                const float s_n  = fmaf(ma, s, a * g);
                az = nz ? az_n : az;
                bz = nz ? bz_n : bz;
                r  = nz ? r_n  : r;
                s  = nz ? s_n  : s;
                g  = nz ? 1.f  : (g + 1.f);   // r_n,s_n already took old f,g
                f  = nz ? 0.f  : f;
            }
        }

        // ---- inclusive Hillis-Steele compose scan across 64 lanes ----
#pragma unroll
        for (int d = 1; d < 64; d <<= 1) {
            const float az_o = __shfl_up(az, d);
            const float bz_o = __shfl_up(bz, d);
            const float r_o  = __shfl_up(r,  d);
            const float s_o  = __shfl_up(s,  d);
            const float f_o  = __shfl_up(f,  d);
            const float g_o  = __shfl_up(g,  d);
            if (lane >= d) {
                bz = fmaf(az, bz_o, bz);
                s  = fmaf(az, s_o, fmaf(r, g_o, s));
                r  = fmaf(az, r_o, r * f_o);
                az = az * az_o;
                g  = fmaf(f, g_o, g);
                f  = f * f_o;
            }
        }

        // ---- exclusive prefix (shift one lane; identity at lane 0) ----
        float azE = __shfl_up(az, 1), bzE = __shfl_up(bz, 1);
        float rE  = __shfl_up(r, 1),  sE  = __shfl_up(s, 1);
        float fE  = __shfl_up(f, 1),  gE  = __shfl_up(g, 1);
        if (lane == 0) {
            azE = 1.f; bzE = 0.f; rE = 0.f; sE = 0.f; fE = 1.f; gE = 0.f;
        }

        // ---- state at this lane's window start (exact) ----
        float Z = fmaf(azE, zs[i], bzE);
        float V = fmaf(azE, vs[i], fmaf(rE, qsx[i], sE));
        float q = fmaf(fE, qsx[i], gE);

        // ---- replay 32 steps, emit out = Z'/V' ----
#pragma unroll
        for (int m = 0; m < 8; ++m) {
#pragma unroll
            for (int k = 0; k < 4; ++k) {
                const float xt = xv[m][k];
                const bool  nz = (xt != 0.f);
                const float Zn = fmaf(ma, Z, a * xt);
                const float Vn = fmaf(ma, V, a * q);
                Z = nz ? Zn : Z;
                V = nz ? Vn : V;
                q = nz ? 1.f : (q + 1.f);
                xv[m][k] = Z * __builtin_amdgcn_rcpf(V);
            }
        }

        // ---- transpose-out -> coalesced stores (drain under next scan) ----
#pragma unroll
        for (int m = 0; m < 8; ++m)
            *(vf4*)(W + lbase + ((m ^ l7) << 2)) = xv[m];
#pragma unroll
        for (int j = 0; j < 8; ++j) {
            const vf4 o = *(const vf4*)(W + j * 256 + goff);
            *(vf4*)(out + (size_t)wid * TLEN + j * 256 + lane * 4) = o;
        }
    }
}

extern "C" void kernel_launch(void* const* d_in, const int* in_sizes, int n_in,
                              void* d_out, int out_size, void* d_ws, size_t ws_size,
                              hipStream_t stream) {
    const float* x     = (const float*)d_in[0];
    const float* alpha = (const float*)d_in[1];
    const float* Z0    = (const float*)d_in[2];
    const float* V0    = (const float*)d_in[3];
    const float* q0    = (const float*)d_in[4];
    float* out = (float*)d_out;

    // 2048 waves x 4 consecutive series each; 512 blocks = 2 blocks/CU
    // (32KB LDS each), 8 waves/CU, vmem-pinned cross-series pipeline.
    dim3 block(256);
    dim3 grid(512);
    croston_kernel<<<grid, block, 0, stream>>>(x, alpha, Z0, V0, q0, out);
}